// Round 16
// baseline (605.543 us; speedup 1.0000x reference)
//
#include <hip/hip_runtime.h>

// Scatter-add edge messages to target atoms per batch:
//   messages: (B=32, E=8192, D=128) f32
//   tgt_indices: (B, E) int32 in [0, N)
//   atom_features_ref: (B, N, D) f32  -- shape-only, never read
//   out: (B, N=2048, D=128) f32
//
// Ladder: R8 191us (LDS value-atomic RMW wall) -> R9 ~70us (segment sort +
// register accum) -> R10/R12/R14 ~67us (load-width, Phase-1-collapse, and
// 8-deep MLP ALL null => permuted single-pass 512B-row gather is memory-
// system-bound at ~2.2 TB/s effective; no reuse exists to exploit).
// R15: the one untested formulation class — fully-coalesced streaming read
// + global_atomic_add_f32 (atomics execute in L2/TCC, a DIFFERENT pipe than
// R8's LDS RMW wall). Reads: 64 lanes x float4 = two full 512B rows per
// instruction. Atomics: lanes cover consecutive f32 of an output row ->
// ~4 lane-ops per 64B line-visit, spread over all TCC channels.
#define BB    32
#define EE    8192
#define NN    2048
#define DD    128
#define OUTF  (BB * NN * DD)   // 8.39M floats

__global__ __launch_bounds__(256) void zero_out_kernel(float4* __restrict__ out4) {
    const int stride = gridDim.x * blockDim.x;
    for (int i = blockIdx.x * blockDim.x + threadIdx.x; i < OUTF / 4; i += stride)
        out4[i] = make_float4(0.f, 0.f, 0.f, 0.f);
}

__global__ __launch_bounds__(256) void scatter_atomic_kernel(
    const float* __restrict__ messages,
    const int*   __restrict__ tgt,
    float*       __restrict__ out)
{
    const int gid = blockIdx.x * 256 + threadIdx.x;  // 8.39M threads
    const int ec  = gid >> 5;          // flat edge id: b*EE + e  (0..262143)
    const int c   = gid & 31;          // float4 chunk within the 128-float row

    const int b = ec >> 13;            // / EE
    const int a = tgt[ec];             // target atom (32 lanes read same value)

    // Coalesced read: 32 consecutive lanes read one full 512 B row;
    // a wave64 instruction covers two rows (1 KiB).
    const float4 v = ((const float4*)messages)[(size_t)ec * (DD / 4) + c];

    // Atomic accumulate: lanes of the 32-group hit a contiguous 512 B span
    // of the output row (stride 16 B per lane per component op).
    float* dst = out + ((size_t)b * NN + a) * DD + c * 4;
    atomicAdd(dst + 0, v.x);
    atomicAdd(dst + 1, v.y);
    atomicAdd(dst + 2, v.z);
    atomicAdd(dst + 3, v.w);
}

extern "C" void kernel_launch(void* const* d_in, const int* in_sizes, int n_in,
                              void* d_out, int out_size, void* d_ws, size_t ws_size,
                              hipStream_t stream) {
    const float* messages = (const float*)d_in[0];
    const int*   tgt      = (const int*)d_in[1];
    // d_in[2] (atom_features_ref) is shape-only; never dereferenced.
    float* out = (float*)d_out;

    // d_out is re-poisoned 0xAA before every timed launch -> zero it first.
    zero_out_kernel<<<2048, 256, 0, stream>>>((float4*)out);

    // One thread per (edge, float4 chunk): 262144 edges x 32 chunks.
    scatter_atomic_kernel<<<(BB * EE * 32) / 256, 256, 0, stream>>>(messages, tgt, out);
}